// Round 2
// baseline (400.816 us; speedup 1.0000x reference)
//
#include <hip/hip_runtime.h>
#include <stdint.h>

// ---------------------------------------------------------------------------
// MultiHeadAttention fused pipeline, MI355X / gfx950.
// Round 2 (desk-checked resubmit; R0/R1 never ran - GPU broker timeouts).
// Split-bf16 (Markidis 3-term) everywhere for fp32-class accuracy:
//   x,W -> (hi,lo) bf16;  A*B ~= Ah*Bh + Al*Bh + Ah*Bl  via K-expansion.
// Kernels: pack_x, pack_wT(x4, coalesced reads), gemm_split<QKV>, attn,
//          gemm_split<OUT>.  Workspace ~110 MB (attn out aliases x-pack).
// ---------------------------------------------------------------------------

#define AS_GLOBAL __attribute__((address_space(1)))
#define AS_LDS    __attribute__((address_space(3)))

typedef __attribute__((ext_vector_type(4))) float f32x4;
typedef __attribute__((ext_vector_type(8))) short bf16x8;
typedef unsigned short u16;
typedef unsigned int   u32;

#define L2E 1.44269504088896340736f

__device__ __forceinline__ u16 f2bf(float f) {
  u32 u = __float_as_uint(f);
  u += 0x7FFFu + ((u >> 16) & 1u);          // RTNE
  return (u16)(u >> 16);
}
__device__ __forceinline__ float bf2f(u16 h) {
  return __uint_as_float(((u32)h) << 16);
}
__device__ __forceinline__ void split2(float f, u16 &hi, u16 &lo) {
  hi = f2bf(f);
  lo = f2bf(f - bf2f(hi));
}
// async global->LDS, 16B per lane; LDS dest is wave-uniform base + lane*16
__device__ __forceinline__ void gl2lds16(const void* g, void* l) {
  __builtin_amdgcn_global_load_lds((const AS_GLOBAL u32*)g, (AS_LDS u32*)l, 16, 0, 0);
}
// element index into a [rows][64] u16 LDS tile, 16B-slot XOR swizzle (G4):
// slot ^= (row & 7) -> 8-slot spread for ds_read_b128
__device__ __forceinline__ int swz(int row, int kc) {   // kc = kcol/8 in [0,8)
  return row * 64 + ((kc ^ (row & 7)) << 3);
}
// MFMA via inline asm (sidesteps builtin operand-type ambiguity on gfx950)
__device__ __forceinline__ void mfma16(f32x4 &acc, bf16x8 a, bf16x8 b) {
  asm volatile("v_mfma_f32_16x16x32_bf16 %0, %1, %2, %0" : "+v"(acc) : "v"(a), "v"(b));
}

// ---------------------------------------------------------------------------
// pack kernels
// ---------------------------------------------------------------------------
__global__ __launch_bounds__(256) void pack_x_kernel(
    const float* __restrict__ src, u16* __restrict__ dh, u16* __restrict__ dl, int n4) {
  int i = blockIdx.x * 256 + threadIdx.x;
  if (i >= n4) return;
  const float4 v = ((const float4*)src)[i];
  ushort4 h, lo;
  split2(v.x, h.x, lo.x); split2(v.y, h.y, lo.y);
  split2(v.z, h.z, lo.z); split2(v.w, h.w, lo.w);
  ((ushort4*)dh)[i] = h;  ((ushort4*)dl)[i] = lo;
}

// w is [K][N] row-major; write hi/lo transposed as [N][K] (GEMM B-frags become
// K-contiguous ds_read_b128). Reads coalesced (lane-consecutive n); writes are
// the scattered side (stores don't stall). K,N = 768.
__global__ __launch_bounds__(256) void pack_wT_kernel(
    const float* __restrict__ w, u16* __restrict__ dh, u16* __restrict__ dl, int K, int N) {
  int i = blockIdx.x * 256 + threadIdx.x;            // over (K/4)*N
  int n = i % N, k0 = (i / N) * 4;
  if (k0 >= K) return;
  ushort4 h, lo;
  split2(w[(size_t)(k0 + 0) * N + n], h.x, lo.x);
  split2(w[(size_t)(k0 + 1) * N + n], h.y, lo.y);
  split2(w[(size_t)(k0 + 2) * N + n], h.z, lo.z);
  split2(w[(size_t)(k0 + 3) * N + n], h.w, lo.w);
  *(ushort4*)&dh[(size_t)n * K + k0] = h;
  *(ushort4*)&dl[(size_t)n * K + k0] = lo;
}

// ---------------------------------------------------------------------------
// GEMM, 128x128 tile, BK=64, 4 waves (2x2 of 64x64), 16x16x32 bf16 MFMA.
// Split-bf16 via 3 K-phases: A phases {Ah, Al, Ah}, B phases {Bh, Bh, Bl}.
// A: [M][K0] row-major (hi/lo). B: [N][K0] (pre-transposed, hi/lo).
// EPI 0: QKV epilogue -> Qh/Ql,Kh/Kl ([bh][s][64], Q scaled 0.125) and V
//        transposed [bh][hd][1024] (hi/lo), biases bq/bk/bv.
// EPI 1: out = acc + bo, fp32 [M][768].
// ---------------------------------------------------------------------------
template<int EPI>
__global__ __launch_bounds__(256) void gemm_split(
    const u16* __restrict__ Ahp, const u16* __restrict__ Alp,
    const u16* __restrict__ Bhp, const u16* __restrict__ Blp,
    int Ntx, int K0,
    const float* __restrict__ b0, const float* __restrict__ b1, const float* __restrict__ b2,
    u16* __restrict__ Qh, u16* __restrict__ Ql,
    u16* __restrict__ Kh, u16* __restrict__ Kl,
    u16* __restrict__ Vth, u16* __restrict__ Vtl,
    float* __restrict__ outF) {
  __shared__ u16 lA[128 * 64];
  __shared__ u16 lB[128 * 64];
  const int bid  = blockIdx.x;
  const int bcol = bid % Ntx;
  const int brow = bid / Ntx;
  const int t = threadIdx.x;
  const int l = t & 63, w = t >> 6;
  const int wm = w >> 1, wn = w & 1;
  const int l15 = l & 15, lg = l >> 4;

  f32x4 acc[4][4] = {};
  const int KP = K0 >> 6;   // k-tiles per phase (12)

  for (int phase = 0; phase < 3; ++phase) {
    const u16* sA = (phase == 1) ? Alp : Ahp;
    const u16* sB = (phase == 2) ? Blp : Bhp;
    for (int ktp = 0; ktp < KP; ++ktp) {
      __syncthreads();
      #pragma unroll
      for (int it = 0; it < 4; ++it) {
        const int ci  = it * 256 + t;
        const int row = ci >> 3;
        const int gs  = (ci & 7) ^ (row & 7);          // pre-swizzled source
        gl2lds16(sA + (size_t)(brow * 128 + row) * K0 + ktp * 64 + gs * 8, &lA[ci * 8]);
        gl2lds16(sB + (size_t)(bcol * 128 + row) * K0 + ktp * 64 + gs * 8, &lB[ci * 8]);
      }
      __syncthreads();
      #pragma unroll
      for (int ks = 0; ks < 2; ++ks) {
        bf16x8 af[4], bfr[4];
        #pragma unroll
        for (int r = 0; r < 4; ++r)
          af[r] = *(const bf16x8*)&lA[swz(wm * 64 + r * 16 + l15, ks * 4 + lg)];
        #pragma unroll
        for (int c = 0; c < 4; ++c)
          bfr[c] = *(const bf16x8*)&lB[swz(wn * 64 + c * 16 + l15, ks * 4 + lg)];
        #pragma unroll
        for (int r = 0; r < 4; ++r)
          #pragma unroll
          for (int c = 0; c < 4; ++c)
            mfma16(acc[r][c], af[r], bfr[c]);
      }
    }
  }

  // epilogue. C/D: col = lane&15, row = (lane>>4)*4 + j  [guide §3, m89-verified]
  #pragma unroll
  for (int r = 0; r < 4; ++r) {
    #pragma unroll
    for (int c = 0; c < 4; ++c) {
      const int m0 = brow * 128 + wm * 64 + r * 16 + lg * 4;
      const int n  = bcol * 128 + wn * 64 + c * 16 + l15;
      if (EPI == 0) {
        const int which = n / 768;
        const int d  = n - which * 768;
        const float bias = (which == 0 ? b0 : which == 1 ? b1 : b2)[d];
        const int hh = d >> 6, hd = d & 63;
        const int b  = m0 >> 10, s0 = m0 & 1023;
        const size_t hb = ((size_t)(b * 12 + hh)) << 16;   // *1024*64
        if (which == 0) {            // Q, fold 1/sqrt(64)
          #pragma unroll
          for (int j = 0; j < 4; ++j) {
            u16 hi, lo; split2((acc[r][c][j] + bias) * 0.125f, hi, lo);
            const size_t a = hb + (size_t)(s0 + j) * 64 + hd;
            Qh[a] = hi; Ql[a] = lo;
          }
        } else if (which == 1) {     // K
          #pragma unroll
          for (int j = 0; j < 4; ++j) {
            u16 hi, lo; split2(acc[r][c][j] + bias, hi, lo);
            const size_t a = hb + (size_t)(s0 + j) * 64 + hd;
            Kh[a] = hi; Kl[a] = lo;
          }
        } else {                     // V, transposed write [bh][hd][s], 8B packed
          ushort4 h4, l4;
          split2(acc[r][c][0] + bias, h4.x, l4.x);
          split2(acc[r][c][1] + bias, h4.y, l4.y);
          split2(acc[r][c][2] + bias, h4.z, l4.z);
          split2(acc[r][c][3] + bias, h4.w, l4.w);
          const size_t a = hb + (size_t)hd * 1024 + s0;
          *(ushort4*)&Vth[a] = h4;
          *(ushort4*)&Vtl[a] = l4;
        }
      } else {
        const float bias = b0[n];
        #pragma unroll
        for (int j = 0; j < 4; ++j)
          outF[(size_t)(m0 + j) * 768 + n] = acc[r][c][j] + bias;
      }
    }
  }
}

// ---------------------------------------------------------------------------
// Flash attention. Grid (16 q-tiles, 96 bh). 4 waves x 16 q-rows, KVBLK=64.
// Q in registers; K [kv][64] and Vt [hd][kv] staged hi/lo in swizzled LDS;
// scores split 3-term; online softmax (16-lane shfl_xor reduce); P hi/lo via
// padded LDS round-trip (stride 72 u16 = 144B, 16B-aligned rows, wave-private
// row range so no cross-wave barrier; DS ops are in-order per wave).
// ---------------------------------------------------------------------------
__global__ __launch_bounds__(256) void attn_kernel(
    const u16* __restrict__ Qh, const u16* __restrict__ Ql,
    const u16* __restrict__ Kh, const u16* __restrict__ Kl,
    const u16* __restrict__ Vth, const u16* __restrict__ Vtl,
    u16* __restrict__ Oh, u16* __restrict__ Ol) {
  __shared__ u16 lK[2][64 * 64];
  __shared__ u16 lV[2][64 * 64];
  __shared__ u16 lP[2][64 * 72];
  const int bh = blockIdx.y, qt = blockIdx.x;
  const int t = threadIdx.x;
  const int l = t & 63, w = t >> 6;
  const int l15 = l & 15, lg = l >> 4;
  const size_t base = (size_t)bh << 16;

  bf16x8 qfh[2], qfl[2];
  {
    const size_t qr = base + (size_t)(qt * 64 + w * 16 + l15) * 64;
    #pragma unroll
    for (int ks = 0; ks < 2; ++ks) {
      qfh[ks] = *(const bf16x8*)&Qh[qr + ks * 32 + lg * 8];
      qfl[ks] = *(const bf16x8*)&Ql[qr + ks * 32 + lg * 8];
    }
  }
  float mrun[4], lrun[4];
  f32x4 Oacc[4] = {};
  #pragma unroll
  for (int j = 0; j < 4; ++j) { mrun[j] = -3.0e38f; lrun[j] = 0.f; }

  for (int kt = 0; kt < 16; ++kt) {
    __syncthreads();
    #pragma unroll
    for (int it = 0; it < 2; ++it) {
      const int ci  = it * 256 + t;
      const int row = ci >> 3;
      const int gs  = (ci & 7) ^ (row & 7);
      const size_t ka = base + (size_t)(kt * 64 + row) * 64 + gs * 8;
      gl2lds16(&Kh[ka],  &lK[0][ci * 8]);
      gl2lds16(&Kl[ka],  &lK[1][ci * 8]);
      const size_t va = base + (size_t)row * 1024 + kt * 64 + gs * 8;
      gl2lds16(&Vth[va], &lV[0][ci * 8]);
      gl2lds16(&Vtl[va], &lV[1][ci * 8]);
    }
    __syncthreads();

    // scores: S = Q . K^T  (split 3-term), wave's 16 q-rows x 64 kv
    f32x4 sc[4] = {};
    #pragma unroll
    for (int ks = 0; ks < 2; ++ks) {
      #pragma unroll
      for (int c = 0; c < 4; ++c) {
        const int idx = swz(c * 16 + l15, ks * 4 + lg);
        const bf16x8 kh = *(const bf16x8*)&lK[0][idx];
        const bf16x8 kl = *(const bf16x8*)&lK[1][idx];
        mfma16(sc[c], qfh[ks], kh);
        mfma16(sc[c], qfl[ks], kh);
        mfma16(sc[c], qfh[ks], kl);
      }
    }

    // online softmax; lane holds rows (lg*4+j), cols c*16+l15
    #pragma unroll
    for (int j = 0; j < 4; ++j) {
      float tm = fmaxf(fmaxf(sc[0][j], sc[1][j]), fmaxf(sc[2][j], sc[3][j]));
      #pragma unroll
      for (int d = 1; d < 16; d <<= 1) tm = fmaxf(tm, __shfl_xor(tm, d, 64));
      const float mnew  = fmaxf(mrun[j], tm);
      const float scale = exp2f((mrun[j] - mnew) * L2E);
      mrun[j] = mnew;
      float ps = 0.f;
      #pragma unroll
      for (int c = 0; c < 4; ++c) {
        const float pv = exp2f((sc[c][j] - mnew) * L2E);
        sc[c][j] = pv;
        ps += pv;
      }
      #pragma unroll
      for (int d = 1; d < 16; d <<= 1) ps += __shfl_xor(ps, d, 64);
      lrun[j] = lrun[j] * scale + ps;
      #pragma unroll
      for (int c2 = 0; c2 < 4; ++c2) Oacc[c2][j] *= scale;
    }

    // P -> LDS (hi/lo), own 16 rows per wave (wave-private, in-order DS pipe)
    #pragma unroll
    for (int c = 0; c < 4; ++c)
      #pragma unroll
      for (int j = 0; j < 4; ++j) {
        u16 hi, lo; split2(sc[c][j], hi, lo);
        const int pa = (w * 16 + lg * 4 + j) * 72 + c * 16 + l15;
        lP[0][pa] = hi; lP[1][pa] = lo;
      }

    // O += P . V  (split 3-term)
    #pragma unroll
    for (int ks = 0; ks < 2; ++ks) {
      const int pr = (w * 16 + l15) * 72 + ks * 32 + lg * 8;
      const bf16x8 ph = *(const bf16x8*)&lP[0][pr];
      const bf16x8 pl = *(const bf16x8*)&lP[1][pr];
      #pragma unroll
      for (int c2 = 0; c2 < 4; ++c2) {
        const int idx = swz(c2 * 16 + l15, ks * 4 + lg);
        const bf16x8 vh = *(const bf16x8*)&lV[0][idx];
        const bf16x8 vl = *(const bf16x8*)&lV[1][idx];
        mfma16(Oacc[c2], ph, vh);
        mfma16(Oacc[c2], pl, vh);
        mfma16(Oacc[c2], ph, vl);
      }
    }
  }

  // epilogue: attn[b, s, h*64+hd] (hi/lo split, feeds out-proj GEMM)
  const int b = bh / 12, hh = bh - b * 12;
  #pragma unroll
  for (int c2 = 0; c2 < 4; ++c2)
    #pragma unroll
    for (int j = 0; j < 4; ++j) {
      const float o = Oacc[c2][j] / lrun[j];
      const int q   = qt * 64 + w * 16 + lg * 4 + j;
      const int col = hh * 64 + c2 * 16 + l15;
      const size_t a = ((size_t)b * 1024 + q) * 768 + col;
      u16 hi, lo; split2(o, hi, lo);
      Oh[a] = hi; Ol[a] = lo;
    }
}

// ---------------------------------------------------------------------------
extern "C" void kernel_launch(void* const* d_in, const int* in_sizes, int n_in,
                              void* d_out, int out_size, void* d_ws, size_t ws_size,
                              hipStream_t stream) {
  const float* x  = (const float*)d_in[0];
  const float* wq = (const float*)d_in[1];
  const float* bq = (const float*)d_in[2];
  const float* wk = (const float*)d_in[3];
  const float* bk = (const float*)d_in[4];
  const float* wv = (const float*)d_in[5];
  const float* bv = (const float*)d_in[6];
  const float* wo = (const float*)d_in[7];
  const float* bo = (const float*)d_in[8];

  const int M = 8192, D = 768, BH = 96;
  char* p = (char*)d_ws;
  auto carve = [&](size_t bytes) -> char* {
    char* r = p; p += (bytes + 255) & ~(size_t)255; return r;
  };
  u16* xh     = (u16*)carve((size_t)M * D * 2);
  u16* xl     = (u16*)carve((size_t)M * D * 2);
  u16* wqkvTh = (u16*)carve((size_t)3 * D * D * 2);
  u16* wqkvTl = (u16*)carve((size_t)3 * D * D * 2);
  u16* woTh   = (u16*)carve((size_t)D * D * 2);
  u16* woTl   = (u16*)carve((size_t)D * D * 2);
  u16* Qh  = (u16*)carve((size_t)BH * 1024 * 64 * 2);
  u16* Ql  = (u16*)carve((size_t)BH * 1024 * 64 * 2);
  u16* Kh  = (u16*)carve((size_t)BH * 1024 * 64 * 2);
  u16* Kl  = (u16*)carve((size_t)BH * 1024 * 64 * 2);
  u16* Vth = (u16*)carve((size_t)BH * 1024 * 64 * 2);
  u16* Vtl = (u16*)carve((size_t)BH * 1024 * 64 * 2);
  // attn output aliases the x-pack buffers (dead after GEMM1; stream-ordered)
  u16* attnh = xh;
  u16* attnl = xl;

  pack_x_kernel<<<(M * D / 4 + 255) / 256, 256, 0, stream>>>(x, xh, xl, M * D / 4);
  const int wgrid = (D * (D / 4) + 255) / 256;
  pack_wT_kernel<<<wgrid, 256, 0, stream>>>(wq, wqkvTh + 0 * (size_t)D * D, wqkvTl + 0 * (size_t)D * D, D, D);
  pack_wT_kernel<<<wgrid, 256, 0, stream>>>(wk, wqkvTh + 1 * (size_t)D * D, wqkvTl + 1 * (size_t)D * D, D, D);
  pack_wT_kernel<<<wgrid, 256, 0, stream>>>(wv, wqkvTh + 2 * (size_t)D * D, wqkvTl + 2 * (size_t)D * D, D, D);
  pack_wT_kernel<<<wgrid, 256, 0, stream>>>(wo, woTh, woTl, D, D);

  // QKV projection: [8192 x 768] x [768 x 2304], K_eff = 3x768 per phase trick
  gemm_split<0><<<(M / 128) * (2304 / 128), 256, 0, stream>>>(
      xh, xl, wqkvTh, wqkvTl, 2304 / 128, D,
      bq, bk, bv, Qh, Ql, Kh, Kl, Vth, Vtl, nullptr);

  attn_kernel<<<dim3(16, BH), 256, 0, stream>>>(Qh, Ql, Kh, Kl, Vth, Vtl, attnh, attnl);

  // out projection: [8192 x 768] x [768 x 768] + bo -> fp32 d_out
  gemm_split<1><<<(M / 128) * (D / 128), 256, 0, stream>>>(
      attnh, attnl, woTh, woTl, D / 128, D,
      bo, nullptr, nullptr,
      nullptr, nullptr, nullptr, nullptr, nullptr, nullptr, (float*)d_out);
}